// Round 12
// baseline (405.976 us; speedup 1.0000x reference)
//
#include <hip/hip_runtime.h>
#include <math.h>

#define NS 1024
#define NV 99
#define NPTS 100
#define H 512

typedef __bf16 bf16x8 __attribute__((ext_vector_type(8)));
typedef __bf16 bf16x4 __attribute__((ext_vector_type(4)));
typedef float f32x4 __attribute__((ext_vector_type(4)));

// async 16B-per-lane global->LDS copy; LDS dest is wave-uniform base + lane*16
#define GLD_LDS16(gp, lp) __builtin_amdgcn_global_load_lds(                 \
    (const __attribute__((address_space(1))) void*)(gp),                    \
    (__attribute__((address_space(3))) void*)(lp), 16, 0, 0)
#define WAIT_VM6()   __builtin_amdgcn_s_waitcnt(0x0f76)   // vmcnt(6) only
#define WAIT_VM12()  __builtin_amdgcn_s_waitcnt(0x0f7c)   // vmcnt(12) only
#define WAIT_VM18()  __builtin_amdgcn_s_waitcnt(0x4f72)   // vmcnt(18) only
#define WAIT_LGKM0() __builtin_amdgcn_s_waitcnt(0xc07f)   // lgkmcnt(0) only
#define SCHED_FENCE() __builtin_amdgcn_sched_barrier(0)
#define MFMA16(a, b, c) __builtin_amdgcn_mfma_f32_16x16x32_bf16(a, b, c, 0, 0, 0)

// ---------------- K1: weight norm, wave-per-row, + folded s0 table ----------------
// Blocks 0..640: 4 weight rows per block (one wave per row, shfl_xor reduce,
// no LDS / no barriers). Blocks 641..838: the s0sin table.
// Modulation weights are written QUAD-INTERLEAVED-TRANSPOSED for k_mod
// coalescing: wT[(k>>2)*2048 + j*4 + (k&3)] = W[j][k]  (j = out row, 512 rows)
// -> a wave's 64 lanes read 64 consecutive float4s (1KB) per k-quad.
// siren W1/W2 bf16 MFMA-fragment-swizzled.
// W2 (and dec) swizzle:
//   swz[((ct*16 + t)*64 + Q*16 + L)*8 + j] = W[ct*16+L][t*32+Q*8+j]
// W1 swizzle row-PERMUTED so layer-1 D-layout == layer-2 B-frag layout:
//   W-row jj sits at (ct, m) with ct = 2*(jj>>5) + ((jj>>2)&1),
//   m = ((jj>>3)&3)*4 + (jj&3)  (bijective on [0,512))
//   => D slot (Q,r) of half h at kb computes channel kb*32 + Q*8 + h*4 + r.
__global__ __launch_bounds__(256) void k_wnorm(
    const float* __restrict__ mv0, const float* __restrict__ mg0,
    const float* __restrict__ mv1, const float* __restrict__ mg1,
    const float* __restrict__ mv2, const float* __restrict__ mg2,
    const float* __restrict__ sv0, const float* __restrict__ sg0,
    const float* __restrict__ sb0,
    const float* __restrict__ sv1, const float* __restrict__ sg1,
    const float* __restrict__ sv2, const float* __restrict__ sg2,
    const float* __restrict__ dv,  const float* __restrict__ dg,
    float* __restrict__ wnM0, float* __restrict__ wnM1, float* __restrict__ wnM2,
    __bf16* __restrict__ W1s, __bf16* __restrict__ W2s, float* __restrict__ wnD,
    float* __restrict__ s0sin)
{
    const int b = blockIdx.x, tid = threadIdx.x;
    if (b >= 641) {   // folded k_s0
        int idx = (b - 641) * 256 + tid;
        if (idx < NV * H) {
            int p = idx >> 9, j = idx & 511;
            float v = sv0[j];
            float w = sg0[j] * v * rsqrtf(v * v);
            float t = (float)p / 99.0f;
            s0sin[idx] = __sinf(30.0f * (t * w + sb0[j]));
        }
        return;
    }
    const int rid = b * 4 + (tid >> 6);
    const int lane = tid & 63;
    if (rid >= 2563) return;

    const float* src; const float* g; int len, j;
    float* dstf = nullptr; __bf16* dstb = nullptr;
    bool perm = false, qint = false;
    if (rid < 512)       { j = rid;        src = mv0 + j*64;  g = mg0; dstf = wnM0;         len = 64;  qint = true; }
    else if (rid < 1024) { j = rid - 512;  src = mv1 + j*576; g = mg1; dstf = wnM1;         len = 576; qint = true; }
    else if (rid < 1536) { j = rid - 1024; src = mv2 + j*576; g = mg2; dstf = wnM2;         len = 576; qint = true; }
    else if (rid < 2048) { j = rid - 1536; src = sv1 + j*512; g = sg1; dstb = W1s;          len = 512; perm = true; }
    else if (rid < 2560) { j = rid - 2048; src = sv2 + j*512; g = sg2; dstb = W2s;          len = 512; }
    else                 { j = rid - 2560; src = dv  + j*512; g = dg;  dstf = wnD + j*512;  len = 512; }

    float ss = 0.f;
    for (int k = lane; k < len; k += 64) { float v = src[k]; ss += v * v; }
#pragma unroll
    for (int o = 1; o < 64; o <<= 1) ss += __shfl_xor(ss, o, 64);
    const float sc = g[j] * rsqrtf(ss);

    if (dstb) {
        if (perm) {
            const int ct = ((j >> 5) << 1) | ((j >> 2) & 1);
            const int m  = (((j >> 3) & 3) << 2) | (j & 3);
            for (int k = lane; k < len; k += 64) {
                int el = ((ct * 16 + (k >> 5)) * 64 + ((k >> 3) & 3) * 16 + m) * 8 + (k & 7);
                dstb[el] = (__bf16)(src[k] * sc);
            }
        } else {
            for (int k = lane; k < len; k += 64) {
                int f  = (j >> 4) * 16 + (k >> 5);
                int el = ((f * 64) + ((k >> 3) & 3) * 16 + (j & 15)) * 8 + (k & 7);
                dstb[el] = (__bf16)(src[k] * sc);
            }
        }
    } else if (qint) {
        for (int k = lane; k < len; k += 64)
            dstf[(k >> 2) * 2048 + j * 4 + (k & 3)] = src[k] * sc;
    } else {
        for (int k = lane; k < len; k += 64) dstf[k] = src[k] * sc;
    }
}

// ---------------- K3: modulation branch, 4 strands per block, 512 threads ----------------
// 512 threads, ONE channel per thread (was 256 thr x 2 channels): same
// per-block weight traffic (each j loaded once, coalesced 1KB/wave/kq) but
// 8 waves/block -> 2 waves/SIMD (was 1) for 2x latency hiding on the
// L2-resident weight loads. Math order per output channel unchanged
// (bit-identical results). Plain __syncthreads only -- zero sync risk.
__global__ __launch_bounds__(512) void k_mod(
    const float* __restrict__ M0T,
    const float* __restrict__ sf, const float* __restrict__ mb0,
    const float* __restrict__ M1T, const float* __restrict__ mb1,
    const float* __restrict__ M2T, const float* __restrict__ mb2,
    float* __restrict__ onem)
{
    const int g0 = blockIdx.x * 4, tid = threadIdx.x;
    __shared__ float z[4][576];   // [strand][64 feat | 512 hidden]

    for (int idx = tid; idx < 4 * 64; idx += 512)
        z[idx >> 6][idx & 63] = sf[(g0 + (idx >> 6)) * 64 + (idx & 63)];
    __syncthreads();

    const int j = tid;            // 0..511: this thread's output channel
    float mreg[4];

    // ---- layer 0 (16 k-quads) ----
    {
        float a[4] = {0.f,0.f,0.f,0.f};
#pragma unroll
        for (int kq = 0; kq < 16; ++kq) {
            float4 w = *(const float4*)(M0T + kq * 2048 + j * 4);
#pragma unroll
            for (int g = 0; g < 4; ++g) {
                float4 zv = *(const float4*)&z[g][kq * 4];
                a[g] += zv.x * w.x + zv.y * w.y + zv.z * w.z + zv.w * w.w;
            }
        }
        const float b = mb0[j];
#pragma unroll
        for (int g = 0; g < 4; ++g) {
            float x = a[g] + b, m = x / (1.f + __expf(-x));
            onem[(g0 + g) * H + j] = 1.f - m; mreg[g] = m;
        }
    }
    __syncthreads();
#pragma unroll
    for (int g = 0; g < 4; ++g) z[g][64 + j] = mreg[g];
    __syncthreads();

    // ---- layer 1 (144 k-quads) ----
    {
        float a[4] = {0.f,0.f,0.f,0.f};
#pragma unroll 4
        for (int kq = 0; kq < 144; ++kq) {
            float4 w = *(const float4*)(M1T + kq * 2048 + j * 4);
#pragma unroll
            for (int g = 0; g < 4; ++g) {
                float4 zv = *(const float4*)&z[g][kq * 4];
                a[g] += zv.x * w.x + zv.y * w.y + zv.z * w.z + zv.w * w.w;
            }
        }
        const float b = mb1[j];
#pragma unroll
        for (int g = 0; g < 4; ++g) {
            float x = a[g] + b, m = x / (1.f + __expf(-x));
            onem[NS * H + (g0 + g) * H + j] = 1.f - m; mreg[g] = m;
        }
    }
    __syncthreads();
#pragma unroll
    for (int g = 0; g < 4; ++g) z[g][64 + j] = mreg[g];
    __syncthreads();

    // ---- layer 2 (144 k-quads) ----
    {
        float a[4] = {0.f,0.f,0.f,0.f};
#pragma unroll 4
        for (int kq = 0; kq < 144; ++kq) {
            float4 w = *(const float4*)(M2T + kq * 2048 + j * 4);
#pragma unroll
            for (int g = 0; g < 4; ++g) {
                float4 zv = *(const float4*)&z[g][kq * 4];
                a[g] += zv.x * w.x + zv.y * w.y + zv.z * w.z + zv.w * w.w;
            }
        }
        const float b = mb2[j];
#pragma unroll
        for (int g = 0; g < 4; ++g) {
            float x = a[g] + b, m = x / (1.f + __expf(-x));
            onem[2 * NS * H + (g0 + g) * H + j] = 1.f - m;
        }
    }
}

// ---------------- K4: fused siren layers 1,2 + decoder (round-2/4 PROVEN, verbatim) ----------------
// 4 waves/block, 128 rows/block. ONE shared 32KB 8-slot LDS ring streams
// W1s..W2s (256 x 4KB chunks); each wave stages its own 1KB quarter per
// chunk so per-wave vmcnt stays exactly counted. 7-chunk lookahead; per
// sub: counted vm wait -> s_barrier -> stage ck+7 -> ds_read ck -> lgkm0
// -> 8 MFMAs. Epilogue global loads issued at kb top, absorbed into the
// in-order vmcnt budget. Layer-1 -> layer-2 handoff fully IN-REGISTER
// (W1 row permutation); L1 kb loop fully unrolled (static nBh indexing).
// SESSION LESSONS (do NOT revisit without asm access):
//  - Any second __launch_bounds__ arg forces VGPR caps -> scratch spills ->
//    spill VMEM ops corrupt the counted-vmcnt ledger (R3/R5/R7 failures).
//  - 8-wave (512-thr) variants structurally exceed the 256-reg 2-wave cap
//    (Bh+nBh ~300 regs) -> unavoidable spills (R7/R8: 656MB WRITE_SIZE).
//  - Alternative wait ledgers (uniform VM6, VM14 kb-top-epi, A/B splits)
//    failed intermittently 4x (R3/R5/R6/R9); only THIS pattern is proven.
__global__ __launch_bounds__(256, 1) void k_main(
    const __bf16* __restrict__ Wstream,
    const float* __restrict__ wnD, const float* __restrict__ sb1,
    const float* __restrict__ sb2, const float* __restrict__ db,
    const float* __restrict__ s0sin, const float* __restrict__ onem,
    float* __restrict__ dirs)
{
    __shared__ __attribute__((aligned(16))) __bf16 wst[8 * 2048];  // 32 KB ring
    const int tid = threadIdx.x;
    const int wave = tid >> 6, lane = tid & 63;
    const int L = lane & 15, Q = lane >> 4;
    const int base = blockIdx.x * 128 + wave * 32;
    const int r0 = base + L, r1 = r0 + 16;
    const int s0 = r0 / 99, p0 = r0 - s0 * 99;
    const int s1 = r1 / 99, p1 = r1 - s1 * 99;
    const int qoff = wave * 512;            // elem offset of this wave's quarter

    // ---- prologue: stage chunks 0..6 (own quarter; 7 loads in flight) ----
#pragma unroll
    for (int c = 0; c < 7; ++c)
        GLD_LDS16(Wstream + c * 2048 + qoff + lane * 8, &wst[c * 2048 + qoff]);

    // ---- build layer-1 B-frags: Bh[t][j] = h1[r][t*32+Q*8+j] (overlaps flight) ----
    bf16x8 Bh0[16], Bh1[16];
    {
        const float* omA = onem + s0 * H;
        const float* tsA = s0sin + p0 * H;
        const float* omB = onem + s1 * H;
        const float* tsB = s0sin + p1 * H;
#pragma unroll
        for (int t = 0; t < 16; ++t) {
            const int k0 = t * 32 + Q * 8;
            f32x4 oa = *(const f32x4*)(omA + k0);
            f32x4 ob = *(const f32x4*)(omA + k0 + 4);
            f32x4 ta = *(const f32x4*)(tsA + k0);
            f32x4 tb = *(const f32x4*)(tsA + k0 + 4);
            bf16x8 v;
            v[0] = (__bf16)(oa[0] * ta[0]); v[1] = (__bf16)(oa[1] * ta[1]);
            v[2] = (__bf16)(oa[2] * ta[2]); v[3] = (__bf16)(oa[3] * ta[3]);
            v[4] = (__bf16)(ob[0] * tb[0]); v[5] = (__bf16)(ob[1] * tb[1]);
            v[6] = (__bf16)(ob[2] * tb[2]); v[7] = (__bf16)(ob[3] * tb[3]);
            Bh0[t] = v;
            oa = *(const f32x4*)(omB + k0);
            ob = *(const f32x4*)(omB + k0 + 4);
            ta = *(const f32x4*)(tsB + k0);
            tb = *(const f32x4*)(tsB + k0 + 4);
            v[0] = (__bf16)(oa[0] * ta[0]); v[1] = (__bf16)(oa[1] * ta[1]);
            v[2] = (__bf16)(oa[2] * ta[2]); v[3] = (__bf16)(oa[3] * ta[3]);
            v[4] = (__bf16)(ob[0] * tb[0]); v[5] = (__bf16)(ob[1] * tb[1]);
            v[6] = (__bf16)(ob[2] * tb[2]); v[7] = (__bf16)(ob[3] * tb[3]);
            Bh1[t] = v;
        }
    }

    // ---- layer 1: chunks 0..127; kb fully unrolled (static nBh indexing) ----
    bf16x8 nBh0[16], nBh1[16];
    {
        const float* om1a = onem + NS * H + s0 * H;
        const float* om1b = onem + NS * H + s1 * H;
#pragma unroll
        for (int kb = 0; kb < 16; ++kb) {
            const int c = kb * 32 + Q * 8;
            const float4 bi0 = *(const float4*)(sb1 + c);
            const float4 bi1 = *(const float4*)(sb1 + c + 4);
            const float4 gA0 = *(const float4*)(om1a + c);
            const float4 gA1 = *(const float4*)(om1a + c + 4);
            const float4 gB0 = *(const float4*)(om1b + c);
            const float4 gB1 = *(const float4*)(om1b + c + 4);
            SCHED_FENCE();   // pin epi loads before sub-loop stages (vmcnt order)
            f32x4 aA0 = {0.f,0.f,0.f,0.f}, aA1 = {0.f,0.f,0.f,0.f};
            f32x4 aB0 = {0.f,0.f,0.f,0.f}, aB1 = {0.f,0.f,0.f,0.f};
#pragma unroll
            for (int sub = 0; sub < 8; ++sub) {
                const int ck = kb * 8 + sub;
                if (sub == 7) { WAIT_VM6(); } else { WAIT_VM12(); }
                __builtin_amdgcn_s_barrier();
                SCHED_FENCE();
                const int nc = ck + 7;                    // <= 134, no wrap
                GLD_LDS16(Wstream + nc * 2048 + qoff + lane * 8,
                          &wst[(nc & 7) * 2048 + qoff]);
                const __bf16* rp = &wst[(ck & 7) * 2048 + lane * 8];
                bf16x8 w0 = *(const bf16x8*)(rp);
                bf16x8 w1 = *(const bf16x8*)(rp + 512);
                bf16x8 w2 = *(const bf16x8*)(rp + 1024);
                bf16x8 w3 = *(const bf16x8*)(rp + 1536);
                WAIT_LGKM0();
                SCHED_FENCE();
                const int t = (sub & 3) * 4;
                if (sub < 4) {
                    aA0 = MFMA16(w0, Bh0[t],     aA0); aA1 = MFMA16(w0, Bh1[t],     aA1);
                    aA0 = MFMA16(w1, Bh0[t + 1], aA0); aA1 = MFMA16(w1, Bh1[t + 1], aA1);
                    aA0 = MFMA16(w2, Bh0[t + 2], aA0); aA1 = MFMA16(w2, Bh1[t + 2], aA1);
                    aA0 = MFMA16(w3, Bh0[t + 3], aA0); aA1 = MFMA16(w3, Bh1[t + 3], aA1);
                } else {
                    aB0 = MFMA16(w0, Bh0[t],     aB0); aB1 = MFMA16(w0, Bh1[t],     aB1);
                    aB0 = MFMA16(w1, Bh0[t + 1], aB0); aB1 = MFMA16(w1, Bh1[t + 1], aB1);
                    aB0 = MFMA16(w2, Bh0[t + 2], aB0); aB1 = MFMA16(w2, Bh1[t + 2], aB1);
                    aB0 = MFMA16(w3, Bh0[t + 3], aB0); aB1 = MFMA16(w3, Bh1[t + 3], aB1);
                }
            }
            // epilogue: channels c..c+3 from half A, c+4..c+7 from half B (permuted W1)
            bf16x8 v;
            v[0] = (__bf16)(gA0.x * __sinf(aA0[0] + bi0.x));
            v[1] = (__bf16)(gA0.y * __sinf(aA0[1] + bi0.y));
            v[2] = (__bf16)(gA0.z * __sinf(aA0[2] + bi0.z));
            v[3] = (__bf16)(gA0.w * __sinf(aA0[3] + bi0.w));
            v[4] = (__bf16)(gA1.x * __sinf(aB0[0] + bi1.x));
            v[5] = (__bf16)(gA1.y * __sinf(aB0[1] + bi1.y));
            v[6] = (__bf16)(gA1.z * __sinf(aB0[2] + bi1.z));
            v[7] = (__bf16)(gA1.w * __sinf(aB0[3] + bi1.w));
            nBh0[kb] = v;
            v[0] = (__bf16)(gB0.x * __sinf(aA1[0] + bi0.x));
            v[1] = (__bf16)(gB0.y * __sinf(aA1[1] + bi0.y));
            v[2] = (__bf16)(gB0.z * __sinf(aA1[2] + bi0.z));
            v[3] = (__bf16)(gB0.w * __sinf(aA1[3] + bi0.w));
            v[4] = (__bf16)(gB1.x * __sinf(aB1[0] + bi1.x));
            v[5] = (__bf16)(gB1.y * __sinf(aB1[1] + bi1.y));
            v[6] = (__bf16)(gB1.z * __sinf(aB1[2] + bi1.z));
            v[7] = (__bf16)(gB1.w * __sinf(aB1[3] + bi1.w));
            nBh1[kb] = v;
        }
    }

    // ---- layer 2: chunks 128..255 + fused decoder ----
    float pA0 = 0.f, pA1 = 0.f, pA2 = 0.f;
    float pB0 = 0.f, pB1 = 0.f, pB2 = 0.f;
    {
        const float* om2a = onem + 2 * NS * H + s0 * H;
        const float* om2b = onem + 2 * NS * H + s1 * H;
#pragma unroll 1
        for (int kb = 0; kb < 16; ++kb) {
            SCHED_FENCE();   // no cross-iteration motion (vmcnt order)
            const int c0 = kb * 32 + Q * 4, c1 = c0 + 16;
            const float4 bi0 = *(const float4*)(sb2 + c0);
            const float4 bi1 = *(const float4*)(sb2 + c1);
            const float4 d00 = *(const float4*)(wnD + c0);
            const float4 d10 = *(const float4*)(wnD + H + c0);
            const float4 d20 = *(const float4*)(wnD + 2 * H + c0);
            const float4 d01 = *(const float4*)(wnD + c1);
            const float4 d11 = *(const float4*)(wnD + H + c1);
            const float4 d21 = *(const float4*)(wnD + 2 * H + c1);
            const float4 ga0 = *(const float4*)(om2a + c0);
            const float4 ga1 = *(const float4*)(om2a + c1);
            const float4 gb0 = *(const float4*)(om2b + c0);
            const float4 gb1 = *(const float4*)(om2b + c1);
            SCHED_FENCE();   // pin 12 epi loads before sub-loop stages
            f32x4 aA0 = {0.f,0.f,0.f,0.f}, aA1 = {0.f,0.f,0.f,0.f};
            f32x4 aB0 = {0.f,0.f,0.f,0.f}, aB1 = {0.f,0.f,0.f,0.f};
#pragma unroll
            for (int sub = 0; sub < 8; ++sub) {
                const int ck = 128 + kb * 8 + sub;        // slot = sub (static)
                if (sub == 7) { WAIT_VM6(); } else { WAIT_VM18(); }
                __builtin_amdgcn_s_barrier();
                SCHED_FENCE();
                const int nc = (ck + 7) & 255;            // tail wraps to 0..6:
                GLD_LDS16(Wstream + nc * 2048 + qoff + lane * 8,  // occupant is
                          &wst[((sub + 7) & 7) * 2048 + qoff]);   // always ck-1
                const __bf16* rp = &wst[sub * 2048 + lane * 8];
                bf16x8 w0 = *(const bf16x8*)(rp);
                bf16x8 w1 = *(const bf16x8*)(rp + 512);
                bf16x8 w2 = *(const bf16x8*)(rp + 1024);
                bf16x8 w3 = *(const bf16x8*)(rp + 1536);
                WAIT_LGKM0();
                SCHED_FENCE();
                const int t = (sub & 3) * 4;
                if (sub < 4) {
                    aA0 = MFMA16(w0, nBh0[t],     aA0); aA1 = MFMA16(w0, nBh1[t],     aA1);
                    aA0 = MFMA16(w1, nBh0[t + 1], aA0); aA1 = MFMA16(w1, nBh1[t + 1], aA1);
                    aA0 = MFMA16(w2, nBh0[t + 2], aA0); aA1 = MFMA16(w2, nBh1[t + 2], aA1);
                    aA0 = MFMA16(w3, nBh0[t + 3], aA0); aA1 = MFMA16(w3, nBh1[t + 3], aA1);
                } else {
                    aB0 = MFMA16(w0, nBh0[t],     aB0); aB1 = MFMA16(w0, nBh1[t],     aB1);
                    aB0 = MFMA16(w1, nBh0[t + 1], aB0); aB1 = MFMA16(w1, nBh1[t + 1], aB1);
                    aB0 = MFMA16(w2, nBh0[t + 2], aB0); aB1 = MFMA16(w2, nBh1[t + 2], aB1);
                    aB0 = MFMA16(w3, nBh0[t + 3], aB0); aB1 = MFMA16(w3, nBh1[t + 3], aB1);
                }
            }
            float h;
            h = ga0.x * __sinf(aA0[0] + bi0.x); pA0 += h * d00.x; pA1 += h * d10.x; pA2 += h * d20.x;
            h = ga0.y * __sinf(aA0[1] + bi0.y); pA0 += h * d00.y; pA1 += h * d10.y; pA2 += h * d20.y;
            h = ga0.z * __sinf(aA0[2] + bi0.z); pA0 += h * d00.z; pA1 += h * d10.z; pA2 += h * d20.z;
            h = ga0.w * __sinf(aA0[3] + bi0.w); pA0 += h * d00.w; pA1 += h * d10.w; pA2 += h * d20.w;
            h = ga1.x * __sinf(aB0[0] + bi1.x); pA0 += h * d01.x; pA1 += h * d11.x; pA2 += h * d21.x;
            h = ga1.y * __sinf(aB0[1] + bi1.y); pA0 += h * d01.y; pA1 += h * d11.y; pA2 += h * d21.y;
            h = ga1.z * __sinf(aB0[2] + bi1.z); pA0 += h * d01.z; pA1 += h * d11.z; pA2 += h * d21.z;
            h = ga1.w * __sinf(aB0[3] + bi1.w); pA0 += h * d01.w; pA1 += h * d11.w; pA2 += h * d21.w;
            h = gb0.x * __sinf(aA1[0] + bi0.x); pB0 += h * d00.x; pB1 += h * d10.x; pB2 += h * d20.x;
            h = gb0.y * __sinf(aA1[1] + bi0.y); pB0 += h * d00.y; pB1 += h * d10.y; pB2 += h * d20.y;
            h = gb0.z * __sinf(aA1[2] + bi0.z); pB0 += h * d00.z; pB1 += h * d10.z; pB2 += h * d20.z;
            h = gb0.w * __sinf(aA1[3] + bi0.w); pB0 += h * d00.w; pB1 += h * d10.w; pB2 += h * d20.w;
            h = gb1.x * __sinf(aB1[0] + bi1.x); pB0 += h * d01.x; pB1 += h * d11.x; pB2 += h * d21.x;
            h = gb1.y * __sinf(aB1[1] + bi1.y); pB0 += h * d01.y; pB1 += h * d11.y; pB2 += h * d21.y;
            h = gb1.z * __sinf(aB1[2] + bi1.z); pB0 += h * d01.z; pB1 += h * d11.z; pB2 += h * d21.z;
            h = gb1.w * __sinf(aB1[3] + bi1.w); pB0 += h * d01.w; pB1 += h * d11.w; pB2 += h * d21.w;
        }
    }

    // reduce decoder partials over the 4 quads (same L, within this wave)
    pA0 += __shfl_xor(pA0, 16, 64); pA0 += __shfl_xor(pA0, 32, 64);
    pA1 += __shfl_xor(pA1, 16, 64); pA1 += __shfl_xor(pA1, 32, 64);
    pA2 += __shfl_xor(pA2, 16, 64); pA2 += __shfl_xor(pA2, 32, 64);
    pB0 += __shfl_xor(pB0, 16, 64); pB0 += __shfl_xor(pB0, 32, 64);
    pB1 += __shfl_xor(pB1, 16, 64); pB1 += __shfl_xor(pB1, 32, 64);
    pB2 += __shfl_xor(pB2, 16, 64); pB2 += __shfl_xor(pB2, 32, 64);
    if (Q == 0) {
        const float d0 = db[0], d1 = db[1], d2 = db[2];
        dirs[r0 * 3 + 0] = 0.01f * (pA0 + d0);
        dirs[r0 * 3 + 1] = 0.01f * (pA1 + d1);
        dirs[r0 * 3 + 2] = 0.01f * (pA2 + d2);
        dirs[r1 * 3 + 0] = 0.01f * (pB0 + d0);
        dirs[r1 * 3 + 1] = 0.01f * (pB1 + d1);
        dirs[r1 * 3 + 2] = 0.01f * (pB2 + d2);
    }
}

// ---------------- K5: cumsum via wave scan (round-10 proven) ----------------
__global__ __launch_bounds__(256) void k_cumsum(const float* __restrict__ dirs,
                                                float* __restrict__ out)
{
    const int wid = blockIdx.x * 4 + (threadIdx.x >> 6);
    const int lane = threadIdx.x & 63;
    const int s = wid / 3, c = wid - 3 * s;
    const float* dp = dirs + (size_t)s * NV * 3 + c;
    float v0 = dp[lane * 3];
    float v1 = (lane < NV - 64) ? dp[(64 + lane) * 3] : 0.f;
#pragma unroll
    for (int off = 1; off < 64; off <<= 1) {
        float t = __shfl_up(v0, off, 64);
        if (lane >= off) v0 += t;
        t = __shfl_up(v1, off, 64);
        if (lane >= off) v1 += t;
    }
    float tot0 = __shfl(v0, 63, 64);
    v1 += tot0;
    float* op = out + (size_t)s * NPTS * 3 + c;
    if (lane == 0) op[0] = 0.f;
    op[(lane + 1) * 3] = v0;
    if (lane < NV - 64) op[(64 + lane + 1) * 3] = v1;
}

extern "C" void kernel_launch(void* const* d_in, const int* in_sizes, int n_in,
                              void* d_out, int out_size, void* d_ws, size_t ws_size,
                              hipStream_t stream)
{
    const float* sf  = (const float*)d_in[0];
    const float* mv0 = (const float*)d_in[1];  const float* mg0 = (const float*)d_in[2];  const float* mb0 = (const float*)d_in[3];
    const float* mv1 = (const float*)d_in[4];  const float* mg1 = (const float*)d_in[5];  const float* mb1 = (const float*)d_in[6];
    const float* mv2 = (const float*)d_in[7];  const float* mg2 = (const float*)d_in[8];  const float* mb2 = (const float*)d_in[9];
    const float* sv0 = (const float*)d_in[10]; const float* sg0 = (const float*)d_in[11]; const float* sb0 = (const float*)d_in[12];
    const float* sv1 = (const float*)d_in[13]; const float* sg1 = (const float*)d_in[14]; const float* sb1 = (const float*)d_in[15];
    const float* sv2 = (const float*)d_in[16]; const float* sg2 = (const float*)d_in[17]; const float* sb2 = (const float*)d_in[18];
    const float* dv  = (const float*)d_in[19]; const float* dg  = (const float*)d_in[20]; const float* dbv = (const float*)d_in[21];

    float* ws = (float*)d_ws;
    float* wnM0  = ws;                 // 32768 (quad-interleaved transposed)
    float* wnM1  = ws + 32768;         // 294912 (quad-interleaved transposed)
    float* wnM2  = ws + 327680;        // 294912 (quad-interleaved transposed)
    float* wnD   = ws + 622592;        // 1536
    float* s0sin = ws + 624128;        // 50688
    float* onem  = ws + 674816;        // 1572864
    float* dirs  = ws + 2247680;       // 304128
    __bf16* W1s  = (__bf16*)(ws + 2551808);   // 512 KB (swizzled, row-permuted)
    __bf16* W2s  = W1s + 262144;              // 512 KB (swizzled) -- contiguous with W1s

    hipLaunchKernelGGL(k_wnorm, dim3(641 + 198), dim3(256), 0, stream,
                       mv0, mg0, mv1, mg1, mv2, mg2, sv0, sg0, sb0,
                       sv1, sg1, sv2, sg2, dv, dg,
                       wnM0, wnM1, wnM2, W1s, W2s, wnD, s0sin);
    hipLaunchKernelGGL(k_mod, dim3(256), dim3(512), 0, stream,
                       wnM0, sf, mb0, wnM1, mb1, wnM2, mb2, onem);
    hipLaunchKernelGGL(k_main, dim3((NS * NV) / 128), dim3(256), 0, stream,
                       W1s, wnD, sb1, sb2, dbv, s0sin, onem, dirs);
    hipLaunchKernelGGL(k_cumsum, dim3(768), dim3(256), 0, stream, dirs, (float*)d_out);
}

// Round 13
// 398.028 us; speedup vs baseline: 1.0200x; 1.0200x over previous
//
#include <hip/hip_runtime.h>
#include <math.h>

#define NS 1024
#define NV 99
#define NPTS 100
#define H 512

typedef __bf16 bf16x8 __attribute__((ext_vector_type(8)));
typedef __bf16 bf16x4 __attribute__((ext_vector_type(4)));
typedef float f32x4 __attribute__((ext_vector_type(4)));

// async 16B-per-lane global->LDS copy; LDS dest is wave-uniform base + lane*16
#define GLD_LDS16(gp, lp) __builtin_amdgcn_global_load_lds(                 \
    (const __attribute__((address_space(1))) void*)(gp),                    \
    (__attribute__((address_space(3))) void*)(lp), 16, 0, 0)
#define WAIT_VM6()   __builtin_amdgcn_s_waitcnt(0x0f76)   // vmcnt(6) only
#define WAIT_VM12()  __builtin_amdgcn_s_waitcnt(0x0f7c)   // vmcnt(12) only
#define WAIT_VM18()  __builtin_amdgcn_s_waitcnt(0x4f72)   // vmcnt(18) only
#define WAIT_LGKM0() __builtin_amdgcn_s_waitcnt(0xc07f)   // lgkmcnt(0) only
#define SCHED_FENCE() __builtin_amdgcn_sched_barrier(0)
#define MFMA16(a, b, c) __builtin_amdgcn_mfma_f32_16x16x32_bf16(a, b, c, 0, 0, 0)

// ---------------- K1: weight norm, wave-per-row, + folded s0 table ----------------
// Blocks 0..640: 4 weight rows per block (one wave per row, shfl_xor reduce,
// no LDS / no barriers). Blocks 641..838: the s0sin table.
// Modulation weights are written QUAD-INTERLEAVED-TRANSPOSED for k_mod
// coalescing: wT[(k>>2)*2048 + j*4 + (k&3)] = W[j][k]  (j = out row, 512 rows)
// -> a wave's 64 lanes read 64 consecutive float4s (1KB) per k-quad.
// siren W1/W2 bf16 MFMA-fragment-swizzled.
// W2 (and dec) swizzle:
//   swz[((ct*16 + t)*64 + Q*16 + L)*8 + j] = W[ct*16+L][t*32+Q*8+j]
// W1 swizzle row-PERMUTED so layer-1 D-layout == layer-2 B-frag layout:
//   W-row jj sits at (ct, m) with ct = 2*(jj>>5) + ((jj>>2)&1),
//   m = ((jj>>3)&3)*4 + (jj&3)  (bijective on [0,512))
//   => D slot (Q,r) of half h at kb computes channel kb*32 + Q*8 + h*4 + r.
__global__ __launch_bounds__(256) void k_wnorm(
    const float* __restrict__ mv0, const float* __restrict__ mg0,
    const float* __restrict__ mv1, const float* __restrict__ mg1,
    const float* __restrict__ mv2, const float* __restrict__ mg2,
    const float* __restrict__ sv0, const float* __restrict__ sg0,
    const float* __restrict__ sb0,
    const float* __restrict__ sv1, const float* __restrict__ sg1,
    const float* __restrict__ sv2, const float* __restrict__ sg2,
    const float* __restrict__ dv,  const float* __restrict__ dg,
    float* __restrict__ wnM0, float* __restrict__ wnM1, float* __restrict__ wnM2,
    __bf16* __restrict__ W1s, __bf16* __restrict__ W2s, float* __restrict__ wnD,
    float* __restrict__ s0sin)
{
    const int b = blockIdx.x, tid = threadIdx.x;
    if (b >= 641) {   // folded k_s0
        int idx = (b - 641) * 256 + tid;
        if (idx < NV * H) {
            int p = idx >> 9, j = idx & 511;
            float v = sv0[j];
            float w = sg0[j] * v * rsqrtf(v * v);
            float t = (float)p / 99.0f;
            s0sin[idx] = __sinf(30.0f * (t * w + sb0[j]));
        }
        return;
    }
    const int rid = b * 4 + (tid >> 6);
    const int lane = tid & 63;
    if (rid >= 2563) return;

    const float* src; const float* g; int len, j;
    float* dstf = nullptr; __bf16* dstb = nullptr;
    bool perm = false, qint = false;
    if (rid < 512)       { j = rid;        src = mv0 + j*64;  g = mg0; dstf = wnM0;         len = 64;  qint = true; }
    else if (rid < 1024) { j = rid - 512;  src = mv1 + j*576; g = mg1; dstf = wnM1;         len = 576; qint = true; }
    else if (rid < 1536) { j = rid - 1024; src = mv2 + j*576; g = mg2; dstf = wnM2;         len = 576; qint = true; }
    else if (rid < 2048) { j = rid - 1536; src = sv1 + j*512; g = sg1; dstb = W1s;          len = 512; perm = true; }
    else if (rid < 2560) { j = rid - 2048; src = sv2 + j*512; g = sg2; dstb = W2s;          len = 512; }
    else                 { j = rid - 2560; src = dv  + j*512; g = dg;  dstf = wnD + j*512;  len = 512; }

    float ss = 0.f;
    for (int k = lane; k < len; k += 64) { float v = src[k]; ss += v * v; }
#pragma unroll
    for (int o = 1; o < 64; o <<= 1) ss += __shfl_xor(ss, o, 64);
    const float sc = g[j] * rsqrtf(ss);

    if (dstb) {
        if (perm) {
            const int ct = ((j >> 5) << 1) | ((j >> 2) & 1);
            const int m  = (((j >> 3) & 3) << 2) | (j & 3);
            for (int k = lane; k < len; k += 64) {
                int el = ((ct * 16 + (k >> 5)) * 64 + ((k >> 3) & 3) * 16 + m) * 8 + (k & 7);
                dstb[el] = (__bf16)(src[k] * sc);
            }
        } else {
            for (int k = lane; k < len; k += 64) {
                int f  = (j >> 4) * 16 + (k >> 5);
                int el = ((f * 64) + ((k >> 3) & 3) * 16 + (j & 15)) * 8 + (k & 7);
                dstb[el] = (__bf16)(src[k] * sc);
            }
        }
    } else if (qint) {
        for (int k = lane; k < len; k += 64)
            dstf[(k >> 2) * 2048 + j * 4 + (k & 3)] = src[k] * sc;
    } else {
        for (int k = lane; k < len; k += 64) dstf[k] = src[k] * sc;
    }
}

// ---------------- K3: modulation branch, 4 strands per block ----------------
// Quad-interleaved transposed weights: every weight load is a coalesced
// dwordx4 (64 lanes x 16B contiguous). Both output rows (j, j+256) share
// each broadcast z read. Math order per accumulator unchanged.
// (R12 tested 512-thr/1-channel: neutral within noise; this 256-thr form
// is the best-measured configuration.)
__global__ __launch_bounds__(256) void k_mod(
    const float* __restrict__ M0T,
    const float* __restrict__ sf, const float* __restrict__ mb0,
    const float* __restrict__ M1T, const float* __restrict__ mb1,
    const float* __restrict__ M2T, const float* __restrict__ mb2,
    float* __restrict__ onem)
{
    const int g0 = blockIdx.x * 4, tid = threadIdx.x;
    __shared__ float z[4][576];   // [strand][64 feat | 512 hidden]

    for (int idx = tid; idx < 4 * 64; idx += 256)
        z[idx >> 6][idx & 63] = sf[(g0 + (idx >> 6)) * 64 + (idx & 63)];
    __syncthreads();

    float mreg[2][4];
    const int j0 = tid, j1 = tid + 256;

    // ---- layer 0 (16 k-quads) ----
    {
        float a0[4] = {0.f,0.f,0.f,0.f}, a1[4] = {0.f,0.f,0.f,0.f};
#pragma unroll
        for (int kq = 0; kq < 16; ++kq) {
            float4 wa = *(const float4*)(M0T + kq * 2048 + j0 * 4);
            float4 wb = *(const float4*)(M0T + kq * 2048 + j1 * 4);
#pragma unroll
            for (int g = 0; g < 4; ++g) {
                float4 zv = *(const float4*)&z[g][kq * 4];
                a0[g] += zv.x * wa.x + zv.y * wa.y + zv.z * wa.z + zv.w * wa.w;
                a1[g] += zv.x * wb.x + zv.y * wb.y + zv.z * wb.z + zv.w * wb.w;
            }
        }
        const float b0 = mb0[j0], b1 = mb0[j1];
#pragma unroll
        for (int g = 0; g < 4; ++g) {
            float x = a0[g] + b0, m = x / (1.f + __expf(-x));
            onem[(g0 + g) * H + j0] = 1.f - m; mreg[0][g] = m;
            x = a1[g] + b1; m = x / (1.f + __expf(-x));
            onem[(g0 + g) * H + j1] = 1.f - m; mreg[1][g] = m;
        }
    }
    __syncthreads();
#pragma unroll
    for (int g = 0; g < 4; ++g) { z[g][64 + j0] = mreg[0][g]; z[g][64 + j1] = mreg[1][g]; }
    __syncthreads();

    // ---- layer 1 (144 k-quads) ----
    {
        float a0[4] = {0.f,0.f,0.f,0.f}, a1[4] = {0.f,0.f,0.f,0.f};
#pragma unroll 4
        for (int kq = 0; kq < 144; ++kq) {
            float4 wa = *(const float4*)(M1T + kq * 2048 + j0 * 4);
            float4 wb = *(const float4*)(M1T + kq * 2048 + j1 * 4);
#pragma unroll
            for (int g = 0; g < 4; ++g) {
                float4 zv = *(const float4*)&z[g][kq * 4];
                a0[g] += zv.x * wa.x + zv.y * wa.y + zv.z * wa.z + zv.w * wa.w;
                a1[g] += zv.x * wb.x + zv.y * wb.y + zv.z * wb.z + zv.w * wb.w;
            }
        }
        const float b0 = mb1[j0], b1 = mb1[j1];
#pragma unroll
        for (int g = 0; g < 4; ++g) {
            float x = a0[g] + b0, m = x / (1.f + __expf(-x));
            onem[NS * H + (g0 + g) * H + j0] = 1.f - m; mreg[0][g] = m;
            x = a1[g] + b1; m = x / (1.f + __expf(-x));
            onem[NS * H + (g0 + g) * H + j1] = 1.f - m; mreg[1][g] = m;
        }
    }
    __syncthreads();
#pragma unroll
    for (int g = 0; g < 4; ++g) { z[g][64 + j0] = mreg[0][g]; z[g][64 + j1] = mreg[1][g]; }
    __syncthreads();

    // ---- layer 2 (144 k-quads) ----
    {
        float a0[4] = {0.f,0.f,0.f,0.f}, a1[4] = {0.f,0.f,0.f,0.f};
#pragma unroll 4
        for (int kq = 0; kq < 144; ++kq) {
            float4 wa = *(const float4*)(M2T + kq * 2048 + j0 * 4);
            float4 wb = *(const float4*)(M2T + kq * 2048 + j1 * 4);
#pragma unroll
            for (int g = 0; g < 4; ++g) {
                float4 zv = *(const float4*)&z[g][kq * 4];
                a0[g] += zv.x * wa.x + zv.y * wa.y + zv.z * wa.z + zv.w * wa.w;
                a1[g] += zv.x * wb.x + zv.y * wb.y + zv.z * wb.z + zv.w * wb.w;
            }
        }
        const float b0 = mb2[j0], b1 = mb2[j1];
#pragma unroll
        for (int g = 0; g < 4; ++g) {
            float x = a0[g] + b0, m = x / (1.f + __expf(-x));
            onem[2 * NS * H + (g0 + g) * H + j0] = 1.f - m;
            x = a1[g] + b1; m = x / (1.f + __expf(-x));
            onem[2 * NS * H + (g0 + g) * H + j1] = 1.f - m;
        }
    }
}

// ---------------- K4: fused siren layers 1,2 + decoder (round-2/4 PROVEN, verbatim) ----------------
// 4 waves/block, 128 rows/block. ONE shared 32KB 8-slot LDS ring streams
// W1s..W2s (256 x 4KB chunks); each wave stages its own 1KB quarter per
// chunk so per-wave vmcnt stays exactly counted. 7-chunk lookahead; per
// sub: counted vm wait -> s_barrier -> stage ck+7 -> ds_read ck -> lgkm0
// -> 8 MFMAs. Epilogue global loads issued at kb top, absorbed into the
// in-order vmcnt budget. Layer-1 -> layer-2 handoff fully IN-REGISTER
// (W1 row permutation); L1 kb loop fully unrolled (static nBh indexing).
// SESSION LESSONS (do NOT revisit without asm access):
//  - Any second __launch_bounds__ arg forces VGPR caps -> scratch spills ->
//    spill VMEM ops corrupt the counted-vmcnt ledger (R3/R5/R7 failures).
//  - 8-wave (512-thr) variants structurally exceed the 256-reg 2-wave cap
//    (Bh+nBh ~300 regs) -> unavoidable spills (R7/R8: 656MB WRITE_SIZE).
//  - Alternative wait ledgers (uniform VM6, VM14 kb-top-epi, A/B splits)
//    failed intermittently 4x (R3/R5/R6/R9); only THIS pattern is proven.
//  - Next real lever (est. ~100 us): break Bh+nBh coexistence to reach
//    2 waves/SIMD -- requires -save-temps disasm to verify zero sub-loop
//    compiler VMEM before trusting any counted-vmcnt ledger.
__global__ __launch_bounds__(256, 1) void k_main(
    const __bf16* __restrict__ Wstream,
    const float* __restrict__ wnD, const float* __restrict__ sb1,
    const float* __restrict__ sb2, const float* __restrict__ db,
    const float* __restrict__ s0sin, const float* __restrict__ onem,
    float* __restrict__ dirs)
{
    __shared__ __attribute__((aligned(16))) __bf16 wst[8 * 2048];  // 32 KB ring
    const int tid = threadIdx.x;
    const int wave = tid >> 6, lane = tid & 63;
    const int L = lane & 15, Q = lane >> 4;
    const int base = blockIdx.x * 128 + wave * 32;
    const int r0 = base + L, r1 = r0 + 16;
    const int s0 = r0 / 99, p0 = r0 - s0 * 99;
    const int s1 = r1 / 99, p1 = r1 - s1 * 99;
    const int qoff = wave * 512;            // elem offset of this wave's quarter

    // ---- prologue: stage chunks 0..6 (own quarter; 7 loads in flight) ----
#pragma unroll
    for (int c = 0; c < 7; ++c)
        GLD_LDS16(Wstream + c * 2048 + qoff + lane * 8, &wst[c * 2048 + qoff]);

    // ---- build layer-1 B-frags: Bh[t][j] = h1[r][t*32+Q*8+j] (overlaps flight) ----
    bf16x8 Bh0[16], Bh1[16];
    {
        const float* omA = onem + s0 * H;
        const float* tsA = s0sin + p0 * H;
        const float* omB = onem + s1 * H;
        const float* tsB = s0sin + p1 * H;
#pragma unroll
        for (int t = 0; t < 16; ++t) {
            const int k0 = t * 32 + Q * 8;
            f32x4 oa = *(const f32x4*)(omA + k0);
            f32x4 ob = *(const f32x4*)(omA + k0 + 4);
            f32x4 ta = *(const f32x4*)(tsA + k0);
            f32x4 tb = *(const f32x4*)(tsA + k0 + 4);
            bf16x8 v;
            v[0] = (__bf16)(oa[0] * ta[0]); v[1] = (__bf16)(oa[1] * ta[1]);
            v[2] = (__bf16)(oa[2] * ta[2]); v[3] = (__bf16)(oa[3] * ta[3]);
            v[4] = (__bf16)(ob[0] * tb[0]); v[5] = (__bf16)(ob[1] * tb[1]);
            v[6] = (__bf16)(ob[2] * tb[2]); v[7] = (__bf16)(ob[3] * tb[3]);
            Bh0[t] = v;
            oa = *(const f32x4*)(omB + k0);
            ob = *(const f32x4*)(omB + k0 + 4);
            ta = *(const f32x4*)(tsB + k0);
            tb = *(const f32x4*)(tsB + k0 + 4);
            v[0] = (__bf16)(oa[0] * ta[0]); v[1] = (__bf16)(oa[1] * ta[1]);
            v[2] = (__bf16)(oa[2] * ta[2]); v[3] = (__bf16)(oa[3] * ta[3]);
            v[4] = (__bf16)(ob[0] * tb[0]); v[5] = (__bf16)(ob[1] * tb[1]);
            v[6] = (__bf16)(ob[2] * tb[2]); v[7] = (__bf16)(ob[3] * tb[3]);
            Bh1[t] = v;
        }
    }

    // ---- layer 1: chunks 0..127; kb fully unrolled (static nBh indexing) ----
    bf16x8 nBh0[16], nBh1[16];
    {
        const float* om1a = onem + NS * H + s0 * H;
        const float* om1b = onem + NS * H + s1 * H;
#pragma unroll
        for (int kb = 0; kb < 16; ++kb) {
            const int c = kb * 32 + Q * 8;
            const float4 bi0 = *(const float4*)(sb1 + c);
            const float4 bi1 = *(const float4*)(sb1 + c + 4);
            const float4 gA0 = *(const float4*)(om1a + c);
            const float4 gA1 = *(const float4*)(om1a + c + 4);
            const float4 gB0 = *(const float4*)(om1b + c);
            const float4 gB1 = *(const float4*)(om1b + c + 4);
            SCHED_FENCE();   // pin epi loads before sub-loop stages (vmcnt order)
            f32x4 aA0 = {0.f,0.f,0.f,0.f}, aA1 = {0.f,0.f,0.f,0.f};
            f32x4 aB0 = {0.f,0.f,0.f,0.f}, aB1 = {0.f,0.f,0.f,0.f};
#pragma unroll
            for (int sub = 0; sub < 8; ++sub) {
                const int ck = kb * 8 + sub;
                if (sub == 7) { WAIT_VM6(); } else { WAIT_VM12(); }
                __builtin_amdgcn_s_barrier();
                SCHED_FENCE();
                const int nc = ck + 7;                    // <= 134, no wrap
                GLD_LDS16(Wstream + nc * 2048 + qoff + lane * 8,
                          &wst[(nc & 7) * 2048 + qoff]);
                const __bf16* rp = &wst[(ck & 7) * 2048 + lane * 8];
                bf16x8 w0 = *(const bf16x8*)(rp);
                bf16x8 w1 = *(const bf16x8*)(rp + 512);
                bf16x8 w2 = *(const bf16x8*)(rp + 1024);
                bf16x8 w3 = *(const bf16x8*)(rp + 1536);
                WAIT_LGKM0();
                SCHED_FENCE();
                const int t = (sub & 3) * 4;
                if (sub < 4) {
                    aA0 = MFMA16(w0, Bh0[t],     aA0); aA1 = MFMA16(w0, Bh1[t],     aA1);
                    aA0 = MFMA16(w1, Bh0[t + 1], aA0); aA1 = MFMA16(w1, Bh1[t + 1], aA1);
                    aA0 = MFMA16(w2, Bh0[t + 2], aA0); aA1 = MFMA16(w2, Bh1[t + 2], aA1);
                    aA0 = MFMA16(w3, Bh0[t + 3], aA0); aA1 = MFMA16(w3, Bh1[t + 3], aA1);
                } else {
                    aB0 = MFMA16(w0, Bh0[t],     aB0); aB1 = MFMA16(w0, Bh1[t],     aB1);
                    aB0 = MFMA16(w1, Bh0[t + 1], aB0); aB1 = MFMA16(w1, Bh1[t + 1], aB1);
                    aB0 = MFMA16(w2, Bh0[t + 2], aB0); aB1 = MFMA16(w2, Bh1[t + 2], aB1);
                    aB0 = MFMA16(w3, Bh0[t + 3], aB0); aB1 = MFMA16(w3, Bh1[t + 3], aB1);
                }
            }
            // epilogue: channels c..c+3 from half A, c+4..c+7 from half B (permuted W1)
            bf16x8 v;
            v[0] = (__bf16)(gA0.x * __sinf(aA0[0] + bi0.x));
            v[1] = (__bf16)(gA0.y * __sinf(aA0[1] + bi0.y));
            v[2] = (__bf16)(gA0.z * __sinf(aA0[2] + bi0.z));
            v[3] = (__bf16)(gA0.w * __sinf(aA0[3] + bi0.w));
            v[4] = (__bf16)(gA1.x * __sinf(aB0[0] + bi1.x));
            v[5] = (__bf16)(gA1.y * __sinf(aB0[1] + bi1.y));
            v[6] = (__bf16)(gA1.z * __sinf(aB0[2] + bi1.z));
            v[7] = (__bf16)(gA1.w * __sinf(aB0[3] + bi1.w));
            nBh0[kb] = v;
            v[0] = (__bf16)(gB0.x * __sinf(aA1[0] + bi0.x));
            v[1] = (__bf16)(gB0.y * __sinf(aA1[1] + bi0.y));
            v[2] = (__bf16)(gB0.z * __sinf(aA1[2] + bi0.z));
            v[3] = (__bf16)(gB0.w * __sinf(aA1[3] + bi0.w));
            v[4] = (__bf16)(gB1.x * __sinf(aB1[0] + bi1.x));
            v[5] = (__bf16)(gB1.y * __sinf(aB1[1] + bi1.y));
            v[6] = (__bf16)(gB1.z * __sinf(aB1[2] + bi1.z));
            v[7] = (__bf16)(gB1.w * __sinf(aB1[3] + bi1.w));
            nBh1[kb] = v;
        }
    }

    // ---- layer 2: chunks 128..255 + fused decoder ----
    float pA0 = 0.f, pA1 = 0.f, pA2 = 0.f;
    float pB0 = 0.f, pB1 = 0.f, pB2 = 0.f;
    {
        const float* om2a = onem + 2 * NS * H + s0 * H;
        const float* om2b = onem + 2 * NS * H + s1 * H;
#pragma unroll 1
        for (int kb = 0; kb < 16; ++kb) {
            SCHED_FENCE();   // no cross-iteration motion (vmcnt order)
            const int c0 = kb * 32 + Q * 4, c1 = c0 + 16;
            const float4 bi0 = *(const float4*)(sb2 + c0);
            const float4 bi1 = *(const float4*)(sb2 + c1);
            const float4 d00 = *(const float4*)(wnD + c0);
            const float4 d10 = *(const float4*)(wnD + H + c0);
            const float4 d20 = *(const float4*)(wnD + 2 * H + c0);
            const float4 d01 = *(const float4*)(wnD + c1);
            const float4 d11 = *(const float4*)(wnD + H + c1);
            const float4 d21 = *(const float4*)(wnD + 2 * H + c1);
            const float4 ga0 = *(const float4*)(om2a + c0);
            const float4 ga1 = *(const float4*)(om2a + c1);
            const float4 gb0 = *(const float4*)(om2b + c0);
            const float4 gb1 = *(const float4*)(om2b + c1);
            SCHED_FENCE();   // pin 12 epi loads before sub-loop stages
            f32x4 aA0 = {0.f,0.f,0.f,0.f}, aA1 = {0.f,0.f,0.f,0.f};
            f32x4 aB0 = {0.f,0.f,0.f,0.f}, aB1 = {0.f,0.f,0.f,0.f};
#pragma unroll
            for (int sub = 0; sub < 8; ++sub) {
                const int ck = 128 + kb * 8 + sub;        // slot = sub (static)
                if (sub == 7) { WAIT_VM6(); } else { WAIT_VM18(); }
                __builtin_amdgcn_s_barrier();
                SCHED_FENCE();
                const int nc = (ck + 7) & 255;            // tail wraps to 0..6:
                GLD_LDS16(Wstream + nc * 2048 + qoff + lane * 8,  // occupant is
                          &wst[((sub + 7) & 7) * 2048 + qoff]);   // always ck-1
                const __bf16* rp = &wst[sub * 2048 + lane * 8];
                bf16x8 w0 = *(const bf16x8*)(rp);
                bf16x8 w1 = *(const bf16x8*)(rp + 512);
                bf16x8 w2 = *(const bf16x8*)(rp + 1024);
                bf16x8 w3 = *(const bf16x8*)(rp + 1536);
                WAIT_LGKM0();
                SCHED_FENCE();
                const int t = (sub & 3) * 4;
                if (sub < 4) {
                    aA0 = MFMA16(w0, nBh0[t],     aA0); aA1 = MFMA16(w0, nBh1[t],     aA1);
                    aA0 = MFMA16(w1, nBh0[t + 1], aA0); aA1 = MFMA16(w1, nBh1[t + 1], aA1);
                    aA0 = MFMA16(w2, nBh0[t + 2], aA0); aA1 = MFMA16(w2, nBh1[t + 2], aA1);
                    aA0 = MFMA16(w3, nBh0[t + 3], aA0); aA1 = MFMA16(w3, nBh1[t + 3], aA1);
                } else {
                    aB0 = MFMA16(w0, nBh0[t],     aB0); aB1 = MFMA16(w0, nBh1[t],     aB1);
                    aB0 = MFMA16(w1, nBh0[t + 1], aB0); aB1 = MFMA16(w1, nBh1[t + 1], aB1);
                    aB0 = MFMA16(w2, nBh0[t + 2], aB0); aB1 = MFMA16(w2, nBh1[t + 2], aB1);
                    aB0 = MFMA16(w3, nBh0[t + 3], aB0); aB1 = MFMA16(w3, nBh1[t + 3], aB1);
                }
            }
            float h;
            h = ga0.x * __sinf(aA0[0] + bi0.x); pA0 += h * d00.x; pA1 += h * d10.x; pA2 += h * d20.x;
            h = ga0.y * __sinf(aA0[1] + bi0.y); pA0 += h * d00.y; pA1 += h * d10.y; pA2 += h * d20.y;
            h = ga0.z * __sinf(aA0[2] + bi0.z); pA0 += h * d00.z; pA1 += h * d10.z; pA2 += h * d20.z;
            h = ga0.w * __sinf(aA0[3] + bi0.w); pA0 += h * d00.w; pA1 += h * d10.w; pA2 += h * d20.w;
            h = ga1.x * __sinf(aB0[0] + bi1.x); pA0 += h * d01.x; pA1 += h * d11.x; pA2 += h * d21.x;
            h = ga1.y * __sinf(aB0[1] + bi1.y); pA0 += h * d01.y; pA1 += h * d11.y; pA2 += h * d21.y;
            h = ga1.z * __sinf(aB0[2] + bi1.z); pA0 += h * d01.z; pA1 += h * d11.z; pA2 += h * d21.z;
            h = ga1.w * __sinf(aB0[3] + bi1.w); pA0 += h * d01.w; pA1 += h * d11.w; pA2 += h * d21.w;
            h = gb0.x * __sinf(aA1[0] + bi0.x); pB0 += h * d00.x; pB1 += h * d10.x; pB2 += h * d20.x;
            h = gb0.y * __sinf(aA1[1] + bi0.y); pB0 += h * d00.y; pB1 += h * d10.y; pB2 += h * d20.y;
            h = gb0.z * __sinf(aA1[2] + bi0.z); pB0 += h * d00.z; pB1 += h * d10.z; pB2 += h * d20.z;
            h = gb0.w * __sinf(aA1[3] + bi0.w); pB0 += h * d00.w; pB1 += h * d10.w; pB2 += h * d20.w;
            h = gb1.x * __sinf(aB1[0] + bi1.x); pB0 += h * d01.x; pB1 += h * d11.x; pB2 += h * d21.x;
            h = gb1.y * __sinf(aB1[1] + bi1.y); pB0 += h * d01.y; pB1 += h * d11.y; pB2 += h * d21.y;
            h = gb1.z * __sinf(aB1[2] + bi1.z); pB0 += h * d01.z; pB1 += h * d11.z; pB2 += h * d21.z;
            h = gb1.w * __sinf(aB1[3] + bi1.w); pB0 += h * d01.w; pB1 += h * d11.w; pB2 += h * d21.w;
        }
    }

    // reduce decoder partials over the 4 quads (same L, within this wave)
    pA0 += __shfl_xor(pA0, 16, 64); pA0 += __shfl_xor(pA0, 32, 64);
    pA1 += __shfl_xor(pA1, 16, 64); pA1 += __shfl_xor(pA1, 32, 64);
    pA2 += __shfl_xor(pA2, 16, 64); pA2 += __shfl_xor(pA2, 32, 64);
    pB0 += __shfl_xor(pB0, 16, 64); pB0 += __shfl_xor(pB0, 32, 64);
    pB1 += __shfl_xor(pB1, 16, 64); pB1 += __shfl_xor(pB1, 32, 64);
    pB2 += __shfl_xor(pB2, 16, 64); pB2 += __shfl_xor(pB2, 32, 64);
    if (Q == 0) {
        const float d0 = db[0], d1 = db[1], d2 = db[2];
        dirs[r0 * 3 + 0] = 0.01f * (pA0 + d0);
        dirs[r0 * 3 + 1] = 0.01f * (pA1 + d1);
        dirs[r0 * 3 + 2] = 0.01f * (pA2 + d2);
        dirs[r1 * 3 + 0] = 0.01f * (pB0 + d0);
        dirs[r1 * 3 + 1] = 0.01f * (pB1 + d1);
        dirs[r1 * 3 + 2] = 0.01f * (pB2 + d2);
    }
}

// ---------------- K5: cumsum via wave scan (round-10 proven) ----------------
__global__ __launch_bounds__(256) void k_cumsum(const float* __restrict__ dirs,
                                                float* __restrict__ out)
{
    const int wid = blockIdx.x * 4 + (threadIdx.x >> 6);
    const int lane = threadIdx.x & 63;
    const int s = wid / 3, c = wid - 3 * s;
    const float* dp = dirs + (size_t)s * NV * 3 + c;
    float v0 = dp[lane * 3];
    float v1 = (lane < NV - 64) ? dp[(64 + lane) * 3] : 0.f;
#pragma unroll
    for (int off = 1; off < 64; off <<= 1) {
        float t = __shfl_up(v0, off, 64);
        if (lane >= off) v0 += t;
        t = __shfl_up(v1, off, 64);
        if (lane >= off) v1 += t;
    }
    float tot0 = __shfl(v0, 63, 64);
    v1 += tot0;
    float* op = out + (size_t)s * NPTS * 3 + c;
    if (lane == 0) op[0] = 0.f;
    op[(lane + 1) * 3] = v0;
    if (lane < NV - 64) op[(64 + lane + 1) * 3] = v1;
}

extern "C" void kernel_launch(void* const* d_in, const int* in_sizes, int n_in,
                              void* d_out, int out_size, void* d_ws, size_t ws_size,
                              hipStream_t stream)
{
    const float* sf  = (const float*)d_in[0];
    const float* mv0 = (const float*)d_in[1];  const float* mg0 = (const float*)d_in[2];  const float* mb0 = (const float*)d_in[3];
    const float* mv1 = (const float*)d_in[4];  const float* mg1 = (const float*)d_in[5];  const float* mb1 = (const float*)d_in[6];
    const float* mv2 = (const float*)d_in[7];  const float* mg2 = (const float*)d_in[8];  const float* mb2 = (const float*)d_in[9];
    const float* sv0 = (const float*)d_in[10]; const float* sg0 = (const float*)d_in[11]; const float* sb0 = (const float*)d_in[12];
    const float* sv1 = (const float*)d_in[13]; const float* sg1 = (const float*)d_in[14]; const float* sb1 = (const float*)d_in[15];
    const float* sv2 = (const float*)d_in[16]; const float* sg2 = (const float*)d_in[17]; const float* sb2 = (const float*)d_in[18];
    const float* dv  = (const float*)d_in[19]; const float* dg  = (const float*)d_in[20]; const float* dbv = (const float*)d_in[21];

    float* ws = (float*)d_ws;
    float* wnM0  = ws;                 // 32768 (quad-interleaved transposed)
    float* wnM1  = ws + 32768;         // 294912 (quad-interleaved transposed)
    float* wnM2  = ws + 327680;        // 294912 (quad-interleaved transposed)
    float* wnD   = ws + 622592;        // 1536
    float* s0sin = ws + 624128;        // 50688
    float* onem  = ws + 674816;        // 1572864
    float* dirs  = ws + 2247680;       // 304128
    __bf16* W1s  = (__bf16*)(ws + 2551808);   // 512 KB (swizzled, row-permuted)
    __bf16* W2s  = W1s + 262144;              // 512 KB (swizzled) -- contiguous with W1s

    hipLaunchKernelGGL(k_wnorm, dim3(641 + 198), dim3(256), 0, stream,
                       mv0, mg0, mv1, mg1, mv2, mg2, sv0, sg0, sb0,
                       sv1, sg1, sv2, sg2, dv, dg,
                       wnM0, wnM1, wnM2, W1s, W2s, wnD, s0sin);
    hipLaunchKernelGGL(k_mod, dim3(256), dim3(256), 0, stream,
                       wnM0, sf, mb0, wnM1, mb1, wnM2, mb2, onem);
    hipLaunchKernelGGL(k_main, dim3((NS * NV) / 128), dim3(256), 0, stream,
                       W1s, wnD, sb1, sb2, dbv, s0sin, onem, dirs);
    hipLaunchKernelGGL(k_cumsum, dim3(768), dim3(256), 0, stream, dirs, (float*)d_out);
}